// Round 1
// baseline (556.168 us; speedup 1.0000x reference)
//
#include <hip/hip_runtime.h>

typedef __bf16 bf16_t;
typedef __bf16 bf16x8 __attribute__((ext_vector_type(8)));
typedef float  f32x4  __attribute__((ext_vector_type(4)));

constexpr int B_   = 64;
constexpr int EMB_ = 256;
constexpr int H_   = 256;
constexpr int NP_  = 512;
constexpr int NC_  = 144;
constexpr int CL_  = 684;
constexpr int CH_  = 342;
constexpr int LL_  = 256;
constexpr int LH_  = 576;
constexpr int OF_  = 256;
constexpr int CTX_ = 1026;
constexpr int CPL_ = 704;   // CL padded to 11*64
constexpr int CPH_ = 384;   // CH padded to 6*64

// ---- workspace layout (float offsets; all 64B aligned) ----
constexpr size_t OFF_EMB  = 0;        // [64][256]
constexpr size_t OFF_PRED = 16384;    // [64][256]
constexpr size_t OFF_UPL  = 32768;    // [64][512]
constexpr size_t OFF_UPH  = 65536;    // [64][512]
constexpr size_t OFF_OFL  = 98304;    // [256][256]
constexpr size_t OFF_OFH  = 163840;   // [576][256]
constexpr size_t OFF_UFL  = 311296;   // [512][256]
constexpr size_t OFF_UFH  = 442368;   // [512][576]
constexpr size_t OFF_EL   = 737280;   // [64][256]
constexpr size_t OFF_EH   = 753664;   // [64][576]
constexpr size_t OFF_CTX  = 790528;   // [64][1026]
constexpr size_t OFF_UAL  = 856192;   // bf16[512][704]
constexpr size_t OFF_UAH  = 1036416;  // bf16[512][384]

__device__ __forceinline__ float sigm(float x) { return 1.f / (1.f + expf(-x)); }

// ---------------- U_a f32 -> padded bf16 ----------------
__global__ __launch_bounds__(256) void k_prep(const float* __restrict__ UaL,
                                              const float* __restrict__ UaH,
                                              bf16_t* __restrict__ dL,
                                              bf16_t* __restrict__ dH) {
  int idx = blockIdx.x * 256 + threadIdx.x;
  if (idx < NP_ * CPL_) {
    int r = idx / CPL_, k = idx - r * CPL_;
    float v = (k < CL_) ? UaL[r * CL_ + k] : 0.f;
    dL[idx] = (bf16_t)v;
  } else {
    int i2 = idx - NP_ * CPL_;
    int r = i2 / CPH_, k = i2 - r * CPH_;
    float v = (k < CH_) ? UaH[r * CH_ + k] : 0.f;
    dH[i2] = (bf16_t)v;
  }
}

// ---------------- embed + GRU1 + u_pred (fused) ----------------
__global__ __launch_bounds__(256) void k_gru1(
    const int* __restrict__ x, const float* __restrict__ hidden,
    const float* __restrict__ embedding,
    const float* __restrict__ w_ih, const float* __restrict__ w_hh,
    const float* __restrict__ b_ih, const float* __restrict__ b_hh,
    const float* __restrict__ UpL, const float* __restrict__ UpH,
    float* __restrict__ embedded, float* __restrict__ pred,
    float* __restrict__ upL, float* __restrict__ upH) {
  int b = blockIdx.x, t = threadIdx.x;
  __shared__ float emb[EMB_], hv[H_], gi[768], gh[768], pr[H_];
  int tok = x[b];
  float ev = embedding[tok * EMB_ + t];
  emb[t] = ev; embedded[b * EMB_ + t] = ev;
  hv[t] = hidden[b * H_ + t];
  __syncthreads();
  for (int j = t; j < 768; j += 256) {
    const float4* wi = (const float4*)(w_ih + (size_t)j * EMB_);
    const float4* wh = (const float4*)(w_hh + (size_t)j * H_);
    float si = b_ih[j], sh = b_hh[j];
    for (int k = 0; k < EMB_ / 4; ++k) {
      float4 a4 = wi[k];
      si += emb[4*k]*a4.x + emb[4*k+1]*a4.y + emb[4*k+2]*a4.z + emb[4*k+3]*a4.w;
      float4 h4 = wh[k];
      sh += hv[4*k]*h4.x + hv[4*k+1]*h4.y + hv[4*k+2]*h4.z + hv[4*k+3]*h4.w;
    }
    gi[j] = si; gh[j] = sh;
  }
  __syncthreads();
  {
    float r = sigm(gi[t] + gh[t]);
    float z = sigm(gi[256+t] + gh[256+t]);
    float n = tanhf(gi[512+t] + r * gh[512+t]);
    float p = (1.f - z) * n + z * hv[t];
    pr[t] = p; pred[b * H_ + t] = p;
  }
  __syncthreads();
  for (int j = t; j < NP_; j += 256) {
    const float4* ul = (const float4*)(UpL + (size_t)j * H_);
    const float4* uh = (const float4*)(UpH + (size_t)j * H_);
    float sl = 0.f, sh2 = 0.f;
    for (int k = 0; k < H_ / 4; ++k) {
      float4 a4 = ul[k];
      sl += pr[4*k]*a4.x + pr[4*k+1]*a4.y + pr[4*k+2]*a4.z + pr[4*k+3]*a4.w;
      float4 c4 = uh[k];
      sh2 += pr[4*k]*c4.x + pr[4*k+1]*c4.y + pr[4*k+2]*c4.z + pr[4*k+3]*c4.w;
    }
    upL[b * NP_ + j] = sl; upH[b * NP_ + j] = sh2;
  }
}

// ---------------- out_f = alpha @ fc_w.T + fc_b  (zero-alpha fast path) ----------------
__global__ __launch_bounds__(256) void k_outf(
    const float* __restrict__ aL, const float* __restrict__ aH,
    const float* __restrict__ fwL, const float* __restrict__ fbL,
    const float* __restrict__ fwH, const float* __restrict__ fbH,
    float* __restrict__ ofL, float* __restrict__ ofH) {
  __shared__ float al[LH_];
  __shared__ int nz;
  int bid = blockIdx.x, t = threadIdx.x;
  bool low = bid < (LL_ * OF_ / 256);
  const float* alpha = low ? aL : aH;
  int L = low ? LL_ : LH_;
  const float* fw = low ? fwL : fwH;
  const float* fb = low ? fbL : fbH;
  float* of = low ? ofL : ofH;
  int row = (low ? bid : bid - (LL_ * OF_ / 256)) * 256 + t;
  if (t == 0) nz = 0;
  __syncthreads();
  int any = 0;
  for (int l = t; l < L; l += 256) { float v = alpha[l]; al[l] = v; any |= (v != 0.f); }
  if (any) atomicOr(&nz, 1);
  __syncthreads();
  float s = fb[row];
  if (nz) {
    const float4* w4 = (const float4*)(fw + (size_t)row * L);
    for (int k = 0; k < L / 4; ++k) {
      float4 a4 = w4[k];
      s += al[4*k]*a4.x + al[4*k+1]*a4.y + al[4*k+2]*a4.z + al[4*k+3]*a4.w;
    }
  }
  of[row] = s;
}

// ---------------- u_f[p,l] = sum_o U_f[p,o] * out_f[l,o] ----------------
__global__ __launch_bounds__(256) void k_uf(
    const float* __restrict__ UfL, const float* __restrict__ UfH,
    const float* __restrict__ ofL, const float* __restrict__ ofH,
    float* __restrict__ ufL, float* __restrict__ ufH) {
  int bid = blockIdx.x, t = threadIdx.x;
  bool low = bid < 64;
  const float* Uf = low ? UfL : UfH;
  const float* of = low ? ofL : ofH;
  float* uf = low ? ufL : ufH;
  int L = low ? LL_ : LH_;
  int p0 = (low ? bid : bid - 64) * 8;
  __shared__ float ufs[8][OF_];
  for (int i = t; i < 8 * OF_; i += 256) ufs[i >> 8][i & 255] = Uf[(size_t)(p0 + (i >> 8)) * OF_ + (i & 255)];
  __syncthreads();
  for (int l = t; l < L; l += 256) {
    const float4* o4 = (const float4*)(of + (size_t)l * OF_);
    float acc[8] = {0,0,0,0,0,0,0,0};
    for (int k = 0; k < OF_ / 4; ++k) {
      float4 v = o4[k];
      #pragma unroll
      for (int i = 0; i < 8; ++i)
        acc[i] += v.x*ufs[i][4*k] + v.y*ufs[i][4*k+1] + v.z*ufs[i][4*k+2] + v.w*ufs[i][4*k+3];
    }
    #pragma unroll
    for (int i = 0; i < 8; ++i) uf[(size_t)(p0 + i) * L + l] = acc[i];
  }
}

// ---------------- fused u_a GEMM (bf16 MFMA) + tanh + nu-reduction -> e_t ----------------
// block: 512 thr (8 waves). One (b, 64-wide l-tile). All 512 p in registers.
// wave w owns p in [w*64, w*64+64): 4 p-subtiles x 4 l-subtiles of 16x16 MFMA.
template<int C, int CP, int L>
__global__ __launch_bounds__(512) void k_ua_et(
    const bf16_t* __restrict__ Uab,   // [NP][CP] bf16, zero-padded
    const float* __restrict__ a,      // [B][C][L]
    const float* __restrict__ up,     // [B][NP]
    const float* __restrict__ uf,     // [NP][L]
    const float* __restrict__ nu,     // [NP]
    float* __restrict__ e_out) {      // [B][L]
  constexpr int KC = CP / 64;
  int lt = blockIdx.x, b = blockIdx.y;
  int l0 = lt * 64;
  int t = threadIdx.x;
  int w = t >> 6, lane = t & 63, g = lane >> 4, ln = lane & 15;

  __shared__ bf16_t Asm[NP_ * 32];  // [512][32]
  __shared__ bf16_t Bsm[64 * 64];   // [l][k], octet-XOR swizzled
  __shared__ float ered[8][64];

  f32x4 acc[4][4];
  #pragma unroll
  for (int i = 0; i < 4; ++i)
    #pragma unroll
    for (int j = 0; j < 4; ++j) acc[i][j] = (f32x4){0.f, 0.f, 0.f, 0.f};

  const float* abase = a + ((size_t)b * C) * L + l0;

  for (int kc = 0; kc < KC; ++kc) {
    { // stage B chunk: 64k x 64l -> bf16 LDS, [l][k] with octet swizzle
      int o = t >> 6, l = t & 63;
      int c0 = kc * 64 + o * 8;
      bf16x8 bv;
      #pragma unroll
      for (int j = 0; j < 8; ++j) {
        int c = c0 + j;
        float v = (c < C) ? abase[(size_t)c * L + l] : 0.f;
        bv[j] = (bf16_t)v;
      }
      *(bf16x8*)&Bsm[l * 64 + ((o ^ (l & 7)) << 3)] = bv;
    }
    #pragma unroll
    for (int half = 0; half < 2; ++half) {
      { // stage A: [512][32] at k0 = kc*64 + half*32
        int oct = t & 3, pr = t >> 2;
        int soff = kc * 64 + half * 32 + oct * 8;
        #pragma unroll
        for (int pass = 0; pass < 4; ++pass) {
          int p = pr + pass * 128;
          *(bf16x8*)&Asm[p * 32 + oct * 8] = *(const bf16x8*)&Uab[(size_t)p * CP + soff];
        }
      }
      __syncthreads();
      bf16x8 af[4];
      #pragma unroll
      for (int ps = 0; ps < 4; ++ps)
        af[ps] = *(bf16x8*)&Asm[(w * 64 + ps * 16 + ln) * 32 + g * 8];
      #pragma unroll
      for (int ts = 0; ts < 4; ++ts) {
        int lrow = ts * 16 + ln;
        int kb = half * 4 + g;
        bf16x8 bfv = *(bf16x8*)&Bsm[lrow * 64 + ((kb ^ (lrow & 7)) << 3)];
        #pragma unroll
        for (int ps = 0; ps < 4; ++ps)
          acc[ps][ts] = __builtin_amdgcn_mfma_f32_16x16x32_bf16(af[ps], bfv, acc[ps][ts], 0, 0, 0);
      }
      __syncthreads();
    }
  }
  // epilogue: e_part[ts] = sum_{ps,reg} nu[p] * tanh(acc + up[b,p] + uf[p,l])
  float ep[4] = {0.f, 0.f, 0.f, 0.f};
  #pragma unroll
  for (int ps = 0; ps < 4; ++ps) {
    int pbase = w * 64 + ps * 16 + 4 * g;
    float upv[4], nuv[4];
    #pragma unroll
    for (int r = 0; r < 4; ++r) { upv[r] = up[b * NP_ + pbase + r]; nuv[r] = nu[pbase + r]; }
    #pragma unroll
    for (int ts = 0; ts < 4; ++ts) {
      int l = l0 + ts * 16 + ln;
      #pragma unroll
      for (int r = 0; r < 4; ++r) {
        float v = acc[ps][ts][r] + upv[r] + uf[(size_t)(pbase + r) * L + l];
        ep[ts] += nuv[r] * tanhf(v);
      }
    }
  }
  #pragma unroll
  for (int ts = 0; ts < 4; ++ts) {
    float v = ep[ts];
    v += __shfl_xor(v, 16, 64);
    v += __shfl_xor(v, 32, 64);
    if (lane < 16) ered[w][ts * 16 + ln] = v;
  }
  __syncthreads();
  if (t < 64) {
    float s = 0.f;
    #pragma unroll
    for (int ww = 0; ww < 8; ++ww) s += ered[ww][t];
    e_out[b * L + l0 + t] = s;
  }
}

// ---------------- softmax(e) + ctx = sum_l alpha_l * a[b,c,l] ----------------
__global__ __launch_bounds__(256) void k_smax_ctx(
    const float* __restrict__ eL, const float* __restrict__ eH,
    const float* __restrict__ aL, const float* __restrict__ aH,
    float* __restrict__ ctx) {
  int bid = blockIdx.x, t = threadIdx.x;
  bool low = bid < 64;
  int b = low ? bid : bid - 64;
  const float* e = low ? eL + b * LL_ : eH + b * LH_;
  const float* a = low ? aL + (size_t)b * CL_ * LL_ : aH + (size_t)b * CH_ * LH_;
  int L = low ? LL_ : LH_;
  int C = low ? CL_ : CH_;
  float* co = ctx + b * CTX_ + (low ? 0 : CL_);
  __shared__ float al[LH_];
  __shared__ float red[4];
  int wid = t >> 6, lane = t & 63;
  float m = -3.4e38f;
  for (int l = t; l < L; l += 256) m = fmaxf(m, e[l]);
  #pragma unroll
  for (int s = 1; s < 64; s <<= 1) m = fmaxf(m, __shfl_xor(m, s, 64));
  if (lane == 0) red[wid] = m;
  __syncthreads();
  m = fmaxf(fmaxf(red[0], red[1]), fmaxf(red[2], red[3]));
  __syncthreads();
  float sum = 0.f;
  for (int l = t; l < L; l += 256) { float v = expf(e[l] - m); al[l] = v; sum += v; }
  #pragma unroll
  for (int s = 1; s < 64; s <<= 1) sum += __shfl_xor(sum, s, 64);
  if (lane == 0) red[wid] = sum;
  __syncthreads();
  float inv = 1.f / (red[0] + red[1] + red[2] + red[3]);
  for (int l = t; l < L; l += 256) al[l] *= inv;
  __syncthreads();
  for (int c = t; c < C; c += 256) {
    const float4* a4 = (const float4*)(a + (size_t)c * L);
    float s2 = 0.f;
    for (int k = 0; k < L / 4; ++k) {
      float4 v = a4[k];
      s2 += al[4*k]*v.x + al[4*k+1]*v.y + al[4*k+2]*v.z + al[4*k+3]*v.w;
    }
    co[c] = s2;
  }
}

// ---------------- GRU2 + final projections ----------------
__global__ __launch_bounds__(256) void k_gru2_out(
    const float* __restrict__ ctx, const float* __restrict__ pred,
    const float* __restrict__ w_ih, const float* __restrict__ w_hh,
    const float* __restrict__ b_ih, const float* __restrict__ b_hh,
    const float* __restrict__ Ws, const float* __restrict__ Wc,
    const float* __restrict__ Wo, const float* __restrict__ embedded,
    float* __restrict__ out) {
  int b = blockIdx.x, t = threadIdx.x;
  __shared__ float cs[CTX_], ps[H_], gi[768], gh[768], nh[H_], sv[EMB_];
  for (int i = t; i < CTX_; i += 256) cs[i] = ctx[b * CTX_ + i];
  ps[t] = pred[b * H_ + t];
  __syncthreads();
  for (int j = t; j < 768; j += 256) {
    const float2* wi2 = (const float2*)(w_ih + (size_t)j * CTX_);
    float si = b_ih[j];
    for (int k = 0; k < CTX_ / 2; ++k) { float2 v = wi2[k]; si += cs[2*k]*v.x + cs[2*k+1]*v.y; }
    const float4* wh4 = (const float4*)(w_hh + (size_t)j * H_);
    float sh = b_hh[j];
    for (int k = 0; k < H_ / 4; ++k) {
      float4 v = wh4[k];
      sh += ps[4*k]*v.x + ps[4*k+1]*v.y + ps[4*k+2]*v.z + ps[4*k+3]*v.w;
    }
    gi[j] = si; gh[j] = sh;
  }
  __syncthreads();
  {
    float r = sigm(gi[t] + gh[t]);
    float z = sigm(gi[256+t] + gh[256+t]);
    float n = tanhf(gi[512+t] + r * gh[512+t]);
    float h = (1.f - z) * n + z * ps[t];
    nh[t] = h;
    out[NC_ * B_ + b * H_ + t] = h;
  }
  __syncthreads();
  {
    const float4* ws4 = (const float4*)(Ws + (size_t)t * H_);
    float s1 = 0.f;
    for (int k = 0; k < H_ / 4; ++k) {
      float4 v = ws4[k];
      s1 += nh[4*k]*v.x + nh[4*k+1]*v.y + nh[4*k+2]*v.z + nh[4*k+3]*v.w;
    }
    const float2* wc2 = (const float2*)(Wc + (size_t)t * CTX_);
    float s2 = 0.f;
    for (int k = 0; k < CTX_ / 2; ++k) { float2 v = wc2[k]; s2 += cs[2*k]*v.x + cs[2*k+1]*v.y; }
    sv[t] = embedded[b * EMB_ + t] + s1 + s2;
  }
  __syncthreads();
  if (t < NC_) {
    const float4* wo4 = (const float4*)(Wo + (size_t)t * EMB_);
    float s = 0.f;
    for (int k = 0; k < EMB_ / 4; ++k) {
      float4 v = wo4[k];
      s += sv[4*k]*v.x + sv[4*k+1]*v.y + sv[4*k+2]*v.z + sv[4*k+3]*v.w;
    }
    out[b * NC_ + t] = s;
  }
}

extern "C" void kernel_launch(void* const* d_in, const int* in_sizes, int n_in,
                              void* d_out, int out_size, void* d_ws, size_t ws_size,
                              hipStream_t stream) {
  (void)in_sizes; (void)n_in; (void)out_size; (void)ws_size;
  const int*   x       = (const int*)  d_in[0];
  const float* hidden  = (const float*)d_in[1];
  const float* lowres  = (const float*)d_in[2];
  const float* highres = (const float*)d_in[3];
  const float* aLow    = (const float*)d_in[4];
  const float* aHigh   = (const float*)d_in[5];
  const float* embd    = (const float*)d_in[6];
  const float* g1wih   = (const float*)d_in[7];
  const float* g1whh   = (const float*)d_in[8];
  const float* g1bih   = (const float*)d_in[9];
  const float* g1bhh   = (const float*)d_in[10];
  const float* g2wih   = (const float*)d_in[11];
  const float* g2whh   = (const float*)d_in[12];
  const float* g2bih   = (const float*)d_in[13];
  const float* g2bhh   = (const float*)d_in[14];
  const float* fwL     = (const float*)d_in[15];
  const float* fbL     = (const float*)d_in[16];
  const float* UpL     = (const float*)d_in[17];
  const float* UaL     = (const float*)d_in[18];
  const float* UfL     = (const float*)d_in[19];
  const float* nuL     = (const float*)d_in[20];
  const float* fwH     = (const float*)d_in[21];
  const float* fbH     = (const float*)d_in[22];
  const float* UpH     = (const float*)d_in[23];
  const float* UaH     = (const float*)d_in[24];
  const float* UfH     = (const float*)d_in[25];
  const float* nuH     = (const float*)d_in[26];
  const float* Wo      = (const float*)d_in[27];
  const float* Ws      = (const float*)d_in[28];
  const float* Wc      = (const float*)d_in[29];

  float* ws  = (float*)d_ws;
  float* out = (float*)d_out;
  float* w_emb  = ws + OFF_EMB;
  float* w_pred = ws + OFF_PRED;
  float* w_upL  = ws + OFF_UPL;
  float* w_upH  = ws + OFF_UPH;
  float* w_ofL  = ws + OFF_OFL;
  float* w_ofH  = ws + OFF_OFH;
  float* w_ufL  = ws + OFF_UFL;
  float* w_ufH  = ws + OFF_UFH;
  float* w_eL   = ws + OFF_EL;
  float* w_eH   = ws + OFF_EH;
  float* w_ctx  = ws + OFF_CTX;
  bf16_t* uaLb  = (bf16_t*)(ws + OFF_UAL);
  bf16_t* uaHb  = (bf16_t*)(ws + OFF_UAH);

  k_prep<<<(NP_ * CPL_ + NP_ * CPH_) / 256, 256, 0, stream>>>(UaL, UaH, uaLb, uaHb);
  k_gru1<<<B_, 256, 0, stream>>>(x, hidden, embd, g1wih, g1whh, g1bih, g1bhh,
                                 UpL, UpH, w_emb, w_pred, w_upL, w_upH);
  k_outf<<<(LL_ * OF_ + LH_ * OF_) / 256, 256, 0, stream>>>(aLow, aHigh, fwL, fbL, fwH, fbH, w_ofL, w_ofH);
  k_uf<<<128, 256, 0, stream>>>(UfL, UfH, w_ofL, w_ofH, w_ufL, w_ufH);
  k_ua_et<CL_, CPL_, LL_><<<dim3(LL_ / 64, B_), 512, 0, stream>>>(uaLb, lowres, w_upL, w_ufL, nuL, w_eL);
  k_ua_et<CH_, CPH_, LH_><<<dim3(LH_ / 64, B_), 512, 0, stream>>>(uaHb, highres, w_upH, w_ufH, nuH, w_eH);
  k_smax_ctx<<<128, 256, 0, stream>>>(w_eL, w_eH, lowres, highres, w_ctx);
  k_gru2_out<<<B_, 256, 0, stream>>>(w_ctx, w_pred, g2wih, g2whh, g2bih, g2bhh,
                                     Ws, Wc, Wo, w_emb, out);
}

// Round 2
// 319.364 us; speedup vs baseline: 1.7415x; 1.7415x over previous
//
#include <hip/hip_runtime.h>

typedef __bf16 bf16_t;
typedef __bf16 bf16x8 __attribute__((ext_vector_type(8)));
typedef float  f32x4  __attribute__((ext_vector_type(4)));

constexpr int B_   = 64;
constexpr int EMB_ = 256;
constexpr int H_   = 256;
constexpr int NP_  = 512;
constexpr int NC_  = 144;
constexpr int CL_  = 684;
constexpr int CH_  = 342;
constexpr int LL_  = 256;
constexpr int LH_  = 576;
constexpr int OF_  = 256;
constexpr int CTX_ = 1026;
constexpr int LDC_ = 1032;  // ctx row stride (16B-aligned rows)
constexpr int CPL_ = 704;   // CL padded to 11*64
constexpr int CPH_ = 384;   // CH padded to 6*64

// ---- workspace layout (float offsets; all 64-float aligned) ----
constexpr size_t OFF_EMB  = 0;        // [64][256]
constexpr size_t OFF_PRED = 16384;    // [64][256]
constexpr size_t OFF_PS1  = 32768;    // [4][64][1536]  gi1|gh1
constexpr size_t OFF_PSUP = 425984;   // [4][64][1792]  upL|upH|gh2
constexpr size_t OFF_PS2  = 884736;   // [8][64][1024]  gi2|wc
constexpr size_t OFF_OFL  = 1409024;  // [256][256]
constexpr size_t OFF_OFH  = 1474560;  // [576][256]
constexpr size_t OFF_UFL  = 1622016;  // [512][256]
constexpr size_t OFF_UFH  = 1753088;  // [512][576]
constexpr size_t OFF_EL   = 2048000;  // [64][256]
constexpr size_t OFF_EH   = 2064384;  // [64][576]
constexpr size_t OFF_CTX  = 2101248;  // [64][1032]
constexpr size_t OFF_UAL  = 2167296;  // bf16[512][704]
constexpr size_t OFF_UAH  = 2347520;  // bf16[512][384]

__device__ __forceinline__ float sigm(float x) { return 1.f / (1.f + expf(-x)); }

// ---------------- U_a f32 -> padded bf16 ----------------
__global__ __launch_bounds__(256) void k_prep(const float* __restrict__ UaL,
                                              const float* __restrict__ UaH,
                                              bf16_t* __restrict__ dL,
                                              bf16_t* __restrict__ dH) {
  int idx = blockIdx.x * 256 + threadIdx.x;
  if (idx < NP_ * CPL_) {
    int r = idx / CPL_, k = idx - r * CPL_;
    float v = (k < CL_) ? UaL[r * CL_ + k] : 0.f;
    dL[idx] = (bf16_t)v;
  } else {
    int i2 = idx - NP_ * CPL_;
    int r = i2 / CPH_, k = i2 - r * CPH_;
    float v = (k < CH_) ? UaH[r * CH_ + k] : 0.f;
    dH[i2] = (bf16_t)v;
  }
}

// ---------------- embedding gather ----------------
__global__ __launch_bounds__(256) void k_embed(const int* __restrict__ x,
                                               const float* __restrict__ embedding,
                                               float* __restrict__ emb) {
  int b = blockIdx.x, t = threadIdx.x;
  emb[b * EMB_ + t] = embedding[(size_t)x[b] * EMB_ + t];
}

// ---------------- generic split-K batched matvec ----------------
// O[s][b][j] = sum_{k in seg s} Xsec[b][k] * Wsec[jr][k]
// block: 32 j x 64 b, 256 thr (thread = 4j x 2b). grid (Nt/32, SK).
__global__ __launch_bounds__(256) void k_mv(
    const float* __restrict__ W0, const float* __restrict__ W1, const float* __restrict__ W2,
    const float* __restrict__ X0, const float* __restrict__ X1, const float* __restrict__ X2,
    int n0, int n1, int K, int ldx, int SK, int Nt,
    float* __restrict__ O) {
  int j0 = blockIdx.x * 32;
  int s  = blockIdx.y;
  const float* W; const float* X; int jr;
  if (j0 < n0)           { W = W0; X = X0; jr = j0; }
  else if (j0 < n0 + n1) { W = W1; X = X1; jr = j0 - n0; }
  else                   { W = W2; X = X2; jr = j0 - n0 - n1; }
  int NCh = (K + 63) >> 6;
  int c0 = (s * NCh) / SK, c1 = ((s + 1) * NCh) / SK;
  __shared__ float sX[64][68];
  __shared__ float sW[32][68];
  int t = threadIdx.x;
  int jg = t >> 5, bg = t & 31;
  float acc[4][2];
  #pragma unroll
  for (int r = 0; r < 4; ++r) { acc[r][0] = 0.f; acc[r][1] = 0.f; }
  for (int c = c0; c < c1; ++c) {
    int kb = c << 6;
    #pragma unroll
    for (int i = 0; i < 16; ++i) {
      int idx = t + (i << 8);
      int row = idx >> 6, col = idx & 63, k = kb + col;
      sX[row][col] = (k < K) ? X[(size_t)row * ldx + k] : 0.f;
    }
    #pragma unroll
    for (int i = 0; i < 8; ++i) {
      int idx = t + (i << 8);
      int row = idx >> 6, col = idx & 63, k = kb + col;
      sW[row][col] = (k < K) ? W[(size_t)(jr + row) * K + k] : 0.f;
    }
    __syncthreads();
    #pragma unroll
    for (int kg = 0; kg < 16; ++kg) {
      float4 xa = *(const float4*)&sX[bg][kg * 4];
      float4 xb = *(const float4*)&sX[bg + 32][kg * 4];
      #pragma unroll
      for (int r = 0; r < 4; ++r) {
        float4 w4 = *(const float4*)&sW[jg * 4 + r][kg * 4];
        acc[r][0] += w4.x*xa.x + w4.y*xa.y + w4.z*xa.z + w4.w*xa.w;
        acc[r][1] += w4.x*xb.x + w4.y*xb.y + w4.z*xb.z + w4.w*xb.w;
      }
    }
    __syncthreads();
  }
  #pragma unroll
  for (int r = 0; r < 4; ++r) {
    int j = j0 + jg * 4 + r;
    O[((size_t)(s * 64) + bg) * Nt + j]      = acc[r][0];
    O[((size_t)(s * 64) + bg + 32) * Nt + j] = acc[r][1];
  }
}

// ---------------- GRU1 activation (combine 4 K-slices) ----------------
__global__ __launch_bounds__(256) void k_act1(const float* __restrict__ PS1,
                                              const float* __restrict__ hidden,
                                              float* __restrict__ pred) {
  int b = blockIdx.x, t = threadIdx.x;
  float gr = 0, gz = 0, gn = 0, hr = 0, hz = 0, hn = 0;
  #pragma unroll
  for (int s = 0; s < 4; ++s) {
    const float* row = PS1 + ((size_t)(s * 64) + b) * 1536;
    gr += row[t]; gz += row[256 + t]; gn += row[512 + t];
    hr += row[768 + t]; hz += row[1024 + t]; hn += row[1280 + t];
  }
  float hv = hidden[b * H_ + t];
  float r = sigm(gr + hr);
  float z = sigm(gz + hz);
  float n = tanhf(gn + r * hn);
  pred[b * H_ + t] = (1.f - z) * n + z * hv;
}

// ---------------- out_f = alpha @ fc_w.T + fc_b  (zero-alpha fast path) ----------------
__global__ __launch_bounds__(256) void k_outf(
    const float* __restrict__ aL, const float* __restrict__ aH,
    const float* __restrict__ fwL, const float* __restrict__ fbL,
    const float* __restrict__ fwH, const float* __restrict__ fbH,
    float* __restrict__ ofL, float* __restrict__ ofH) {
  __shared__ float al[LH_];
  __shared__ int nz;
  int bid = blockIdx.x, t = threadIdx.x;
  bool low = bid < (LL_ * OF_ / 256);
  const float* alpha = low ? aL : aH;
  int L = low ? LL_ : LH_;
  const float* fw = low ? fwL : fwH;
  const float* fb = low ? fbL : fbH;
  float* of = low ? ofL : ofH;
  int row = (low ? bid : bid - (LL_ * OF_ / 256)) * 256 + t;
  if (t == 0) nz = 0;
  __syncthreads();
  int any = 0;
  for (int l = t; l < L; l += 256) { float v = alpha[l]; al[l] = v; any |= (v != 0.f); }
  if (any) atomicOr(&nz, 1);
  __syncthreads();
  float s = fb[row];
  if (nz) {
    const float4* w4 = (const float4*)(fw + (size_t)row * L);
    for (int k = 0; k < L / 4; ++k) {
      float4 a4 = w4[k];
      s += al[4*k]*a4.x + al[4*k+1]*a4.y + al[4*k+2]*a4.z + al[4*k+3]*a4.w;
    }
  }
  of[row] = s;
}

// ---------------- u_f[p,l] = sum_o U_f[p,o] * out_f[l,o] ----------------
__global__ __launch_bounds__(256) void k_uf(
    const float* __restrict__ UfL, const float* __restrict__ UfH,
    const float* __restrict__ ofL, const float* __restrict__ ofH,
    float* __restrict__ ufL, float* __restrict__ ufH) {
  int bid = blockIdx.x, t = threadIdx.x;
  bool low = bid < 64;
  const float* Uf = low ? UfL : UfH;
  const float* of = low ? ofL : ofH;
  float* uf = low ? ufL : ufH;
  int L = low ? LL_ : LH_;
  int p0 = (low ? bid : bid - 64) * 8;
  __shared__ float ufs[8][OF_];
  for (int i = t; i < 8 * OF_; i += 256) ufs[i >> 8][i & 255] = Uf[(size_t)(p0 + (i >> 8)) * OF_ + (i & 255)];
  __syncthreads();
  for (int l = t; l < L; l += 256) {
    const float4* o4 = (const float4*)(of + (size_t)l * OF_);
    float acc[8] = {0,0,0,0,0,0,0,0};
    for (int k = 0; k < OF_ / 4; ++k) {
      float4 v = o4[k];
      #pragma unroll
      for (int i = 0; i < 8; ++i)
        acc[i] += v.x*ufs[i][4*k] + v.y*ufs[i][4*k+1] + v.z*ufs[i][4*k+2] + v.w*ufs[i][4*k+3];
    }
    #pragma unroll
    for (int i = 0; i < 8; ++i) uf[(size_t)(p0 + i) * L + l] = acc[i];
  }
}

// ---------------- fused u_a GEMM (bf16 MFMA) + tanh + nu-reduction -> e_t ----------------
template<int C, int CP, int L>
__global__ __launch_bounds__(512) void k_ua_et(
    const bf16_t* __restrict__ Uab,   // [NP][CP] bf16, zero-padded
    const float* __restrict__ a,      // [B][C][L]
    const float* __restrict__ up,     // PSUP base [4][64][1792]
    int upoff,                        // column offset of this scale's u_pred
    const float* __restrict__ uf,     // [NP][L]
    const float* __restrict__ nu,     // [NP]
    float* __restrict__ e_out) {      // [B][L]
  constexpr int KC = CP / 64;
  int lt = blockIdx.x, b = blockIdx.y;
  int l0 = lt * 64;
  int t = threadIdx.x;
  int w = t >> 6, lane = t & 63, g = lane >> 4, ln = lane & 15;

  __shared__ bf16_t Asm[NP_ * 32];  // [512][32]
  __shared__ bf16_t Bsm[64 * 64];   // [l][k], octet-XOR swizzled
  __shared__ float ered[8][64];

  f32x4 acc[4][4];
  #pragma unroll
  for (int i = 0; i < 4; ++i)
    #pragma unroll
    for (int j = 0; j < 4; ++j) acc[i][j] = (f32x4){0.f, 0.f, 0.f, 0.f};

  const float* abase = a + ((size_t)b * C) * L + l0;

  for (int kc = 0; kc < KC; ++kc) {
    { // stage B chunk: 64k x 64l -> bf16 LDS, [l][k] with octet swizzle
      int o = t >> 6, l = t & 63;
      int c0 = kc * 64 + o * 8;
      bf16x8 bv;
      #pragma unroll
      for (int j = 0; j < 8; ++j) {
        int c = c0 + j;
        float v = (c < C) ? abase[(size_t)c * L + l] : 0.f;
        bv[j] = (bf16_t)v;
      }
      *(bf16x8*)&Bsm[l * 64 + ((o ^ (l & 7)) << 3)] = bv;
    }
    #pragma unroll
    for (int half = 0; half < 2; ++half) {
      { // stage A: [512][32] at k0 = kc*64 + half*32
        int oct = t & 3, pr = t >> 2;
        int soff = kc * 64 + half * 32 + oct * 8;
        #pragma unroll
        for (int pass = 0; pass < 4; ++pass) {
          int p = pr + pass * 128;
          *(bf16x8*)&Asm[p * 32 + oct * 8] = *(const bf16x8*)&Uab[(size_t)p * CP + soff];
        }
      }
      __syncthreads();
      bf16x8 af[4];
      #pragma unroll
      for (int ps = 0; ps < 4; ++ps)
        af[ps] = *(bf16x8*)&Asm[(w * 64 + ps * 16 + ln) * 32 + g * 8];
      #pragma unroll
      for (int ts = 0; ts < 4; ++ts) {
        int lrow = ts * 16 + ln;
        int kb = half * 4 + g;
        bf16x8 bfv = *(bf16x8*)&Bsm[lrow * 64 + ((kb ^ (lrow & 7)) << 3)];
        #pragma unroll
        for (int ps = 0; ps < 4; ++ps)
          acc[ps][ts] = __builtin_amdgcn_mfma_f32_16x16x32_bf16(af[ps], bfv, acc[ps][ts], 0, 0, 0);
      }
      __syncthreads();
    }
  }
  // epilogue: e_part[ts] = sum_{ps,reg} nu[p] * tanh(acc + up[b,p] + uf[p,l])
  float ep[4] = {0.f, 0.f, 0.f, 0.f};
  #pragma unroll
  for (int ps = 0; ps < 4; ++ps) {
    int pbase = w * 64 + ps * 16 + 4 * g;
    float upv[4], nuv[4];
    #pragma unroll
    for (int r = 0; r < 4; ++r) {
      float u = 0.f;
      #pragma unroll
      for (int s = 0; s < 4; ++s)
        u += up[((size_t)(s * 64) + b) * 1792 + upoff + pbase + r];
      upv[r] = u; nuv[r] = nu[pbase + r];
    }
    #pragma unroll
    for (int ts = 0; ts < 4; ++ts) {
      int l = l0 + ts * 16 + ln;
      #pragma unroll
      for (int r = 0; r < 4; ++r) {
        float v = acc[ps][ts][r] + upv[r] + uf[(size_t)(pbase + r) * L + l];
        ep[ts] += nuv[r] * tanhf(v);
      }
    }
  }
  #pragma unroll
  for (int ts = 0; ts < 4; ++ts) {
    float v = ep[ts];
    v += __shfl_xor(v, 16, 64);
    v += __shfl_xor(v, 32, 64);
    if (lane < 16) ered[w][ts * 16 + ln] = v;
  }
  __syncthreads();
  if (t < 64) {
    float s = 0.f;
    #pragma unroll
    for (int ww = 0; ww < 8; ++ww) s += ered[ww][t];
    e_out[b * L + l0 + t] = s;
  }
}

// ---------------- softmax(e) + ctx = sum_l alpha_l * a[b,c,l] ----------------
__global__ __launch_bounds__(256) void k_smax_ctx(
    const float* __restrict__ eL, const float* __restrict__ eH,
    const float* __restrict__ aL, const float* __restrict__ aH,
    float* __restrict__ ctx) {
  int bid = blockIdx.x, t = threadIdx.x;
  bool low = bid < 64;
  int b = low ? bid : bid - 64;
  const float* e = low ? eL + b * LL_ : eH + b * LH_;
  const float* a = low ? aL + (size_t)b * CL_ * LL_ : aH + (size_t)b * CH_ * LH_;
  int L = low ? LL_ : LH_;
  int C = low ? CL_ : CH_;
  float* co = ctx + (size_t)b * LDC_ + (low ? 0 : CL_);
  __shared__ float al[LH_];
  __shared__ float red[4];
  int wid = t >> 6, lane = t & 63;
  float m = -3.4e38f;
  for (int l = t; l < L; l += 256) m = fmaxf(m, e[l]);
  #pragma unroll
  for (int s = 1; s < 64; s <<= 1) m = fmaxf(m, __shfl_xor(m, s, 64));
  if (lane == 0) red[wid] = m;
  __syncthreads();
  m = fmaxf(fmaxf(red[0], red[1]), fmaxf(red[2], red[3]));
  __syncthreads();
  float sum = 0.f;
  for (int l = t; l < L; l += 256) { float v = expf(e[l] - m); al[l] = v; sum += v; }
  #pragma unroll
  for (int s = 1; s < 64; s <<= 1) sum += __shfl_xor(sum, s, 64);
  if (lane == 0) red[wid] = sum;
  __syncthreads();
  float inv = 1.f / (red[0] + red[1] + red[2] + red[3]);
  for (int l = t; l < L; l += 256) al[l] *= inv;
  __syncthreads();
  for (int c = t; c < C; c += 256) {
    const float4* a4 = (const float4*)(a + (size_t)c * L);
    float s2 = 0.f;
    for (int k = 0; k < L / 4; ++k) {
      float4 v = a4[k];
      s2 += al[4*k]*v.x + al[4*k+1]*v.y + al[4*k+2]*v.z + al[4*k+3]*v.w;
    }
    co[c] = s2;
  }
}

// ---------------- GRU2 act + w_s + sv + out projection (per-batch fused) ----------------
__global__ __launch_bounds__(256) void k_final(
    const float* __restrict__ PS2,    // [8][64][1024]  gi2|wc
    const float* __restrict__ PSUP,   // [4][64][1792]  (gh2 at cols 1024..1792)
    const float* __restrict__ pred,
    const float* __restrict__ emb,
    const float* __restrict__ Ws, const float* __restrict__ Wo,
    const float* __restrict__ b_ih, const float* __restrict__ b_hh,
    float* __restrict__ out) {
  int b = blockIdx.x, t = threadIdx.x;
  __shared__ float nh[H_], sv[EMB_];
  float gr = b_ih[t], gz = b_ih[256 + t], gn = b_ih[512 + t];
  float wc_t = 0.f;
  #pragma unroll
  for (int s = 0; s < 8; ++s) {
    const float* row = PS2 + ((size_t)(s * 64) + b) * 1024;
    gr += row[t]; gz += row[256 + t]; gn += row[512 + t];
    wc_t += row[768 + t];
  }
  float hr = b_hh[t], hz = b_hh[256 + t], hn = b_hh[512 + t];
  #pragma unroll
  for (int s = 0; s < 4; ++s) {
    const float* row = PSUP + ((size_t)(s * 64) + b) * 1792;
    hr += row[1024 + t]; hz += row[1280 + t]; hn += row[1536 + t];
  }
  float hv = pred[b * H_ + t];
  float r = sigm(gr + hr);
  float z = sigm(gz + hz);
  float n = tanhf(gn + r * hn);
  float h = (1.f - z) * n + z * hv;
  nh[t] = h;
  out[NC_ * B_ + b * H_ + t] = h;
  __syncthreads();
  { // w_s[t] = sum_k nh[k] * Ws[t][k]; sv = emb + w_s + wc
    const float4* ws4 = (const float4*)(Ws + (size_t)t * H_);
    float s1 = 0.f;
    for (int k = 0; k < H_ / 4; ++k) {
      float4 v = ws4[k];
      s1 += nh[4*k]*v.x + nh[4*k+1]*v.y + nh[4*k+2]*v.z + nh[4*k+3]*v.w;
    }
    sv[t] = emb[b * EMB_ + t] + s1 + wc_t;
  }
  __syncthreads();
  if (t < NC_) {
    const float4* wo4 = (const float4*)(Wo + (size_t)t * EMB_);
    float s = 0.f;
    for (int k = 0; k < EMB_ / 4; ++k) {
      float4 v = wo4[k];
      s += sv[4*k]*v.x + sv[4*k+1]*v.y + sv[4*k+2]*v.z + sv[4*k+3]*v.w;
    }
    out[b * NC_ + t] = s;
  }
}

extern "C" void kernel_launch(void* const* d_in, const int* in_sizes, int n_in,
                              void* d_out, int out_size, void* d_ws, size_t ws_size,
                              hipStream_t stream) {
  (void)in_sizes; (void)n_in; (void)out_size; (void)ws_size;
  const int*   x       = (const int*)  d_in[0];
  const float* hidden  = (const float*)d_in[1];
  const float* lowres  = (const float*)d_in[2];
  const float* highres = (const float*)d_in[3];
  const float* aLow    = (const float*)d_in[4];
  const float* aHigh   = (const float*)d_in[5];
  const float* embd    = (const float*)d_in[6];
  const float* g1wih   = (const float*)d_in[7];
  const float* g1whh   = (const float*)d_in[8];
  const float* g1bih   = (const float*)d_in[9];
  const float* g1bhh   = (const float*)d_in[10];
  const float* g2wih   = (const float*)d_in[11];
  const float* g2whh   = (const float*)d_in[12];
  const float* g2bih   = (const float*)d_in[13];
  const float* g2bhh   = (const float*)d_in[14];
  const float* fwL     = (const float*)d_in[15];
  const float* fbL     = (const float*)d_in[16];
  const float* UpL     = (const float*)d_in[17];
  const float* UaL     = (const float*)d_in[18];
  const float* UfL     = (const float*)d_in[19];
  const float* nuL     = (const float*)d_in[20];
  const float* fwH     = (const float*)d_in[21];
  const float* fbH     = (const float*)d_in[22];
  const float* UpH     = (const float*)d_in[23];
  const float* UaH     = (const float*)d_in[24];
  const float* UfH     = (const float*)d_in[25];
  const float* nuH     = (const float*)d_in[26];
  const float* Wo      = (const float*)d_in[27];
  const float* Ws      = (const float*)d_in[28];
  const float* Wc      = (const float*)d_in[29];

  float* ws  = (float*)d_ws;
  float* out = (float*)d_out;
  float* w_emb  = ws + OFF_EMB;
  float* w_pred = ws + OFF_PRED;
  float* w_ps1  = ws + OFF_PS1;
  float* w_psup = ws + OFF_PSUP;
  float* w_ps2  = ws + OFF_PS2;
  float* w_ofL  = ws + OFF_OFL;
  float* w_ofH  = ws + OFF_OFH;
  float* w_ufL  = ws + OFF_UFL;
  float* w_ufH  = ws + OFF_UFH;
  float* w_eL   = ws + OFF_EL;
  float* w_eH   = ws + OFF_EH;
  float* w_ctx  = ws + OFF_CTX;
  bf16_t* uaLb  = (bf16_t*)(ws + OFF_UAL);
  bf16_t* uaHb  = (bf16_t*)(ws + OFF_UAH);

  // independent prep
  k_prep<<<(NP_ * CPL_ + NP_ * CPH_) / 256, 256, 0, stream>>>(UaL, UaH, uaLb, uaHb);
  k_embed<<<B_, 256, 0, stream>>>(x, embd, w_emb);
  k_outf<<<(LL_ * OF_ + LH_ * OF_) / 256, 256, 0, stream>>>(aLow, aHigh, fwL, fbL, fwH, fbH, w_ofL, w_ofH);
  k_uf<<<128, 256, 0, stream>>>(UfL, UfH, w_ofL, w_ofH, w_ufL, w_ufH);

  // GRU1: gi1|gh1 (N=1536, K=256, SK=4)
  k_mv<<<dim3(48, 4), 256, 0, stream>>>(g1wih, g1whh, nullptr,
                                        w_emb, hidden, nullptr,
                                        768, 768, 256, 256, 4, 1536, w_ps1);
  k_act1<<<B_, 256, 0, stream>>>(w_ps1, hidden, w_pred);

  // upL|upH|gh2 (N=1792, K=256, SK=4), X = pred
  k_mv<<<dim3(56, 4), 256, 0, stream>>>(UpL, UpH, g2whh,
                                        w_pred, w_pred, w_pred,
                                        512, 512, 256, 256, 4, 1792, w_psup);

  // attention
  k_ua_et<CL_, CPL_, LL_><<<dim3(LL_ / 64, B_), 512, 0, stream>>>(uaLb, lowres, w_psup, 0,   w_ufL, nuL, w_eL);
  k_ua_et<CH_, CPH_, LH_><<<dim3(LH_ / 64, B_), 512, 0, stream>>>(uaHb, highres, w_psup, 512, w_ufH, nuH, w_eH);
  k_smax_ctx<<<128, 256, 0, stream>>>(w_eL, w_eH, lowres, highres, w_ctx);

  // gi2|wc (N=1024, K=1026, SK=8), X = ctx (ld 1032)
  k_mv<<<dim3(32, 8), 256, 0, stream>>>(g2wih, Wc, nullptr,
                                        w_ctx, w_ctx, nullptr,
                                        768, 256, CTX_, LDC_, 8, 1024, w_ps2);

  // GRU2 act + projections
  k_final<<<B_, 256, 0, stream>>>(w_ps2, w_psup, w_pred, w_emb, Ws, Wo, g2bih, g2bhh, out);
}

// Round 3
// 308.224 us; speedup vs baseline: 1.8044x; 1.0361x over previous
//
#include <hip/hip_runtime.h>

typedef __bf16 bf16_t;
typedef __bf16 bf16x8 __attribute__((ext_vector_type(8)));
typedef float  f32x4  __attribute__((ext_vector_type(4)));

constexpr int B_   = 64;
constexpr int EMB_ = 256;
constexpr int H_   = 256;
constexpr int NP_  = 512;
constexpr int NC_  = 144;
constexpr int CL_  = 684;
constexpr int CH_  = 342;
constexpr int LL_  = 256;
constexpr int LH_  = 576;
constexpr int OF_  = 256;
constexpr int CTX_ = 1026;
constexpr int LDC_ = 1032;  // ctx row stride
constexpr int CPL_ = 704;   // CL padded to 11*64
constexpr int CPH_ = 384;   // CH padded to 6*64

// ---- workspace layout (float offsets) ----
constexpr size_t OFF_EMB  = 0;        // [64][256]
constexpr size_t OFF_PRED = 16384;    // [64][256]
constexpr size_t OFF_PS1  = 32768;    // [4][64][1536]  gi1|gh1
constexpr size_t OFF_PSUP = 425984;   // [4][64][1792]  upL|upH|gh2
constexpr size_t OFF_PS2  = 884736;   // [8][64][1024]  gi2|wc
constexpr size_t OFF_OFL  = 1409024;  // [256][256]
constexpr size_t OFF_OFH  = 1474560;  // [576][256]
constexpr size_t OFF_UFL  = 1622016;  // [512][256]
constexpr size_t OFF_UFH  = 1753088;  // [512][576]
constexpr size_t OFF_EL   = 2048000;  // [64][256]
constexpr size_t OFF_EH   = 2064384;  // [64][576]
constexpr size_t OFF_CTX  = 2101248;  // [64][1032]
constexpr size_t OFF_UAL  = 2167296;  // bf16[512][704]
constexpr size_t OFF_UAH  = 2347520;  // bf16[512][384]
constexpr size_t OFF_ALL  = 2445824;  // [64][256] alpha low
constexpr size_t OFF_ALH  = 2462208;  // [64][576] alpha high

__device__ __forceinline__ float sigm(float x) { return 1.f / (1.f + expf(-x)); }

// ---------------- merged front: U_a->bf16 | embed | out_f ----------------
__global__ __launch_bounds__(256) void k_front(
    const float* __restrict__ UaL, const float* __restrict__ UaH,
    bf16_t* __restrict__ dL, bf16_t* __restrict__ dH,
    const int* __restrict__ x, const float* __restrict__ embedding,
    float* __restrict__ emb,
    const float* __restrict__ aL, const float* __restrict__ aH,
    const float* __restrict__ fwL, const float* __restrict__ fbL,
    const float* __restrict__ fwH, const float* __restrict__ fbH,
    float* __restrict__ ofL, float* __restrict__ ofH) {
  __shared__ float al[LH_];
  __shared__ int nz;
  int bid = blockIdx.x, t = threadIdx.x;
  if (bid < 2176) {  // prep
    int idx = bid * 256 + t;
    if (idx < NP_ * CPL_) {
      int r = idx / CPL_, k = idx - r * CPL_;
      float v = (k < CL_) ? UaL[r * CL_ + k] : 0.f;
      dL[idx] = (bf16_t)v;
    } else {
      int i2 = idx - NP_ * CPL_;
      int r = i2 / CPH_, k = i2 - r * CPH_;
      float v = (k < CH_) ? UaH[r * CH_ + k] : 0.f;
      dH[i2] = (bf16_t)v;
    }
    return;
  }
  if (bid < 2240) {  // embed
    int b = bid - 2176;
    emb[b * EMB_ + t] = embedding[(size_t)x[b] * EMB_ + t];
    return;
  }
  // out_f (zero-alpha fast path)
  int bo = bid - 2240;
  bool low = bo < 256;
  const float* alpha = low ? aL : aH;
  int L = low ? LL_ : LH_;
  const float* fw = low ? fwL : fwH;
  const float* fb = low ? fbL : fbH;
  float* of = low ? ofL : ofH;
  int row = (low ? bo : bo - 256) * 256 + t;
  if (t == 0) nz = 0;
  __syncthreads();
  int any = 0;
  for (int l = t; l < L; l += 256) { float v = alpha[l]; al[l] = v; any |= (v != 0.f); }
  if (any) atomicOr(&nz, 1);
  __syncthreads();
  float s = fb[row];
  if (nz) {
    const float4* w4 = (const float4*)(fw + (size_t)row * L);
    for (int k = 0; k < L / 4; ++k) {
      float4 a4 = w4[k];
      s += al[4*k]*a4.x + al[4*k+1]*a4.y + al[4*k+2]*a4.z + al[4*k+3]*a4.w;
    }
  }
  of[row] = s;
}

// ---------------- generic split-K batched matvec ----------------
__global__ __launch_bounds__(256) void k_mv(
    const float* __restrict__ W0, const float* __restrict__ W1, const float* __restrict__ W2,
    const float* __restrict__ X0, const float* __restrict__ X1, const float* __restrict__ X2,
    int n0, int n1, int K, int ldx, int SK, int Nt,
    float* __restrict__ O) {
  int j0 = blockIdx.x * 32;
  int s  = blockIdx.y;
  const float* W; const float* X; int jr;
  if (j0 < n0)           { W = W0; X = X0; jr = j0; }
  else if (j0 < n0 + n1) { W = W1; X = X1; jr = j0 - n0; }
  else                   { W = W2; X = X2; jr = j0 - n0 - n1; }
  int NCh = (K + 63) >> 6;
  int c0 = (s * NCh) / SK, c1 = ((s + 1) * NCh) / SK;
  __shared__ float sX[64][68];
  __shared__ float sW[32][68];
  int t = threadIdx.x;
  int jg = t >> 5, bg = t & 31;
  float acc[4][2];
  #pragma unroll
  for (int r = 0; r < 4; ++r) { acc[r][0] = 0.f; acc[r][1] = 0.f; }
  for (int c = c0; c < c1; ++c) {
    int kb = c << 6;
    #pragma unroll
    for (int i = 0; i < 16; ++i) {
      int idx = t + (i << 8);
      int row = idx >> 6, col = idx & 63, k = kb + col;
      sX[row][col] = (k < K) ? X[(size_t)row * ldx + k] : 0.f;
    }
    #pragma unroll
    for (int i = 0; i < 8; ++i) {
      int idx = t + (i << 8);
      int row = idx >> 6, col = idx & 63, k = kb + col;
      sW[row][col] = (k < K) ? W[(size_t)(jr + row) * K + k] : 0.f;
    }
    __syncthreads();
    #pragma unroll
    for (int kg = 0; kg < 16; ++kg) {
      float4 xa = *(const float4*)&sX[bg][kg * 4];
      float4 xb = *(const float4*)&sX[bg + 32][kg * 4];
      #pragma unroll
      for (int r = 0; r < 4; ++r) {
        float4 w4 = *(const float4*)&sW[jg * 4 + r][kg * 4];
        acc[r][0] += w4.x*xa.x + w4.y*xa.y + w4.z*xa.z + w4.w*xa.w;
        acc[r][1] += w4.x*xb.x + w4.y*xb.y + w4.z*xb.z + w4.w*xb.w;
      }
    }
    __syncthreads();
  }
  #pragma unroll
  for (int r = 0; r < 4; ++r) {
    int j = j0 + jg * 4 + r;
    O[((size_t)(s * 64) + bg) * Nt + j]      = acc[r][0];
    O[((size_t)(s * 64) + bg + 32) * Nt + j] = acc[r][1];
  }
}

// ---------------- GRU1 activation (combine 4 K-slices) ----------------
__global__ __launch_bounds__(256) void k_act1(const float* __restrict__ PS1,
                                              const float* __restrict__ hidden,
                                              float* __restrict__ pred) {
  int b = blockIdx.x, t = threadIdx.x;
  float gr = 0, gz = 0, gn = 0, hr = 0, hz = 0, hn = 0;
  #pragma unroll
  for (int s = 0; s < 4; ++s) {
    const float* row = PS1 + ((size_t)(s * 64) + b) * 1536;
    gr += row[t]; gz += row[256 + t]; gn += row[512 + t];
    hr += row[768 + t]; hz += row[1024 + t]; hn += row[1280 + t];
  }
  float hv = hidden[b * H_ + t];
  float r = sigm(gr + hr);
  float z = sigm(gz + hz);
  float n = tanhf(gn + r * hn);
  pred[b * H_ + t] = (1.f - z) * n + z * hv;
}

// ---------------- u_f[p,l] = sum_o U_f[p,o] * out_f[l,o] ----------------
__global__ __launch_bounds__(256) void k_uf(
    const float* __restrict__ UfL, const float* __restrict__ UfH,
    const float* __restrict__ ofL, const float* __restrict__ ofH,
    float* __restrict__ ufL, float* __restrict__ ufH) {
  int bid = blockIdx.x, t = threadIdx.x;
  bool low = bid < 64;
  const float* Uf = low ? UfL : UfH;
  const float* of = low ? ofL : ofH;
  float* uf = low ? ufL : ufH;
  int L = low ? LL_ : LH_;
  int p0 = (low ? bid : bid - 64) * 8;
  __shared__ float ufs[8][OF_];
  for (int i = t; i < 8 * OF_; i += 256) ufs[i >> 8][i & 255] = Uf[(size_t)(p0 + (i >> 8)) * OF_ + (i & 255)];
  __syncthreads();
  for (int l = t; l < L; l += 256) {
    const float4* o4 = (const float4*)(of + (size_t)l * OF_);
    float acc[8] = {0,0,0,0,0,0,0,0};
    for (int k = 0; k < OF_ / 4; ++k) {
      float4 v = o4[k];
      #pragma unroll
      for (int i = 0; i < 8; ++i)
        acc[i] += v.x*ufs[i][4*k] + v.y*ufs[i][4*k+1] + v.z*ufs[i][4*k+2] + v.w*ufs[i][4*k+3];
    }
    #pragma unroll
    for (int i = 0; i < 8; ++i) uf[(size_t)(p0 + i) * L + l] = acc[i];
  }
}

// ---------------- merged u_a GEMM (bf16 MFMA) + tanh + nu-reduce -> e ----------------
// grid (13, 64): bx<4 -> low tile bx; bx>=4 -> high tile bx-4
__global__ __launch_bounds__(512, 4) void k_ua(
    const bf16_t* __restrict__ uaL, const bf16_t* __restrict__ uaH,
    const float* __restrict__ lowres, const float* __restrict__ highres,
    const float* __restrict__ psup,
    const float* __restrict__ ufL, const float* __restrict__ ufH,
    const float* __restrict__ nuL, const float* __restrict__ nuH,
    float* __restrict__ eL, float* __restrict__ eH) {
  int bx = blockIdx.x, b = blockIdx.y;
  bool lo = bx < 4;
  int lt = lo ? bx : bx - 4;
  int C  = lo ? CL_ : CH_;
  int CP = lo ? CPL_ : CPH_;
  int L  = lo ? LL_ : LH_;
  int upoff = lo ? 0 : 512;
  const bf16_t* Uab = lo ? uaL : uaH;
  const float* a    = lo ? lowres : highres;
  const float* uf   = lo ? ufL : ufH;
  const float* nu   = lo ? nuL : nuH;
  float* e_out      = lo ? eL : eH;
  int KC = CP >> 6;
  int l0 = lt * 64;
  int t = threadIdx.x;
  int w = t >> 6, lane = t & 63, g = lane >> 4, ln = lane & 15;

  __shared__ bf16_t Asm[NP_ * 32];  // [512][32]
  __shared__ bf16_t Bsm[64 * 64];   // [l][k], octet-XOR swizzled
  __shared__ float ered[8][64];

  f32x4 acc[4][4];
  #pragma unroll
  for (int i = 0; i < 4; ++i)
    #pragma unroll
    for (int j = 0; j < 4; ++j) acc[i][j] = (f32x4){0.f, 0.f, 0.f, 0.f};

  const float* abase = a + ((size_t)b * C) * L + l0;

  for (int kc = 0; kc < KC; ++kc) {
    { // stage B chunk: 64k x 64l
      int o = t >> 6, l = t & 63;
      int c0 = kc * 64 + o * 8;
      bf16x8 bv;
      #pragma unroll
      for (int j = 0; j < 8; ++j) {
        int c = c0 + j;
        float v = (c < C) ? abase[(size_t)c * L + l] : 0.f;
        bv[j] = (bf16_t)v;
      }
      *(bf16x8*)&Bsm[l * 64 + ((o ^ (l & 7)) << 3)] = bv;
    }
    #pragma unroll
    for (int half = 0; half < 2; ++half) {
      { // stage A: [512][32]
        int oct = t & 3, pr = t >> 2;
        int soff = kc * 64 + half * 32 + oct * 8;
        #pragma unroll
        for (int pass = 0; pass < 4; ++pass) {
          int p = pr + pass * 128;
          *(bf16x8*)&Asm[p * 32 + oct * 8] = *(const bf16x8*)&Uab[(size_t)p * CP + soff];
        }
      }
      __syncthreads();
      bf16x8 af[4];
      #pragma unroll
      for (int ps = 0; ps < 4; ++ps)
        af[ps] = *(bf16x8*)&Asm[(w * 64 + ps * 16 + ln) * 32 + g * 8];
      #pragma unroll
      for (int ts = 0; ts < 4; ++ts) {
        int lrow = ts * 16 + ln;
        int kb = half * 4 + g;
        bf16x8 bfv = *(bf16x8*)&Bsm[lrow * 64 + ((kb ^ (lrow & 7)) << 3)];
        #pragma unroll
        for (int ps = 0; ps < 4; ++ps)
          acc[ps][ts] = __builtin_amdgcn_mfma_f32_16x16x32_bf16(af[ps], bfv, acc[ps][ts], 0, 0, 0);
      }
      __syncthreads();
    }
  }
  float ep[4] = {0.f, 0.f, 0.f, 0.f};
  #pragma unroll
  for (int ps = 0; ps < 4; ++ps) {
    int pbase = w * 64 + ps * 16 + 4 * g;
    float upv[4], nuv[4];
    #pragma unroll
    for (int r = 0; r < 4; ++r) {
      float u = 0.f;
      #pragma unroll
      for (int s = 0; s < 4; ++s)
        u += psup[((size_t)(s * 64) + b) * 1792 + upoff + pbase + r];
      upv[r] = u; nuv[r] = nu[pbase + r];
    }
    #pragma unroll
    for (int ts = 0; ts < 4; ++ts) {
      int l = l0 + ts * 16 + ln;
      #pragma unroll
      for (int r = 0; r < 4; ++r) {
        float v = acc[ps][ts][r] + upv[r] + uf[(size_t)(pbase + r) * L + l];
        ep[ts] += nuv[r] * tanhf(v);
      }
    }
  }
  #pragma unroll
  for (int ts = 0; ts < 4; ++ts) {
    float v = ep[ts];
    v += __shfl_xor(v, 16, 64);
    v += __shfl_xor(v, 32, 64);
    if (lane < 16) ered[w][ts * 16 + ln] = v;
  }
  __syncthreads();
  if (t < 64) {
    float s = 0.f;
    #pragma unroll
    for (int ww = 0; ww < 8; ++ww) s += ered[ww][t];
    e_out[b * L + l0 + t] = s;
  }
}

// ---------------- softmax(e) -> alpha ----------------
__global__ __launch_bounds__(256) void k_smax(
    const float* __restrict__ eL, const float* __restrict__ eH,
    float* __restrict__ alL, float* __restrict__ alH) {
  int bid = blockIdx.x, t = threadIdx.x;
  bool low = bid < 64;
  int b = low ? bid : bid - 64;
  const float* e = low ? eL + b * LL_ : eH + b * LH_;
  float* ag = low ? alL + b * LL_ : alH + b * LH_;
  int L = low ? LL_ : LH_;
  __shared__ float al[LH_];
  __shared__ float red[4];
  int wid = t >> 6, lane = t & 63;
  float m = -3.4e38f;
  for (int l = t; l < L; l += 256) m = fmaxf(m, e[l]);
  #pragma unroll
  for (int s = 1; s < 64; s <<= 1) m = fmaxf(m, __shfl_xor(m, s, 64));
  if (lane == 0) red[wid] = m;
  __syncthreads();
  m = fmaxf(fmaxf(red[0], red[1]), fmaxf(red[2], red[3]));
  __syncthreads();
  float sum = 0.f;
  for (int l = t; l < L; l += 256) { float v = expf(e[l] - m); al[l] = v; sum += v; }
  #pragma unroll
  for (int s = 1; s < 64; s <<= 1) sum += __shfl_xor(sum, s, 64);
  if (lane == 0) red[wid] = sum;
  __syncthreads();
  float inv = 1.f / (red[0] + red[1] + red[2] + red[3]);
  for (int l = t; l < L; l += 256) ag[l] = al[l] * inv;
}

// ---------------- ctx[b,c] = sum_l alpha[b,l] a[b,c,l]  (grid 17 x 64) ----------------
__global__ __launch_bounds__(256) void k_ctx(
    const float* __restrict__ alL, const float* __restrict__ alH,
    const float* __restrict__ lowres, const float* __restrict__ highres,
    float* __restrict__ ctx) {
  int tile = blockIdx.x, b = blockIdx.y, t = threadIdx.x;
  bool low = tile < 11;
  int C = low ? CL_ : CH_;
  int L = low ? LL_ : LH_;
  int c0 = (low ? tile : tile - 11) * 64;
  const float* al = (low ? alL + b * LL_ : alH + b * LH_);
  const float* a  = (low ? lowres : highres) + ((size_t)b * C) * L;
  float* co = ctx + (size_t)b * LDC_ + (low ? 0 : CL_) + c0;
  int rows = min(64, C - c0);
  __shared__ float als[LH_];
  __shared__ float red[64][4];
  for (int l = t; l < L; l += 256) als[l] = al[l];
  __syncthreads();
  int r = t >> 2, q = t & 3;
  int Lq = L >> 2;
  float s = 0.f;
  if (r < rows) {
    const float4* a4 = (const float4*)(a + (size_t)(c0 + r) * L + q * Lq);
    const float* alq = als + q * Lq;
    for (int k = 0; k < (Lq >> 2); ++k) {
      float4 v = a4[k];
      s += alq[4*k]*v.x + alq[4*k+1]*v.y + alq[4*k+2]*v.z + alq[4*k+3]*v.w;
    }
  }
  red[r][q] = s;
  __syncthreads();
  if (q == 0 && r < rows)
    co[r] = red[r][0] + red[r][1] + red[r][2] + red[r][3];
}

// ---------------- GRU2 act + w_s + sv + out projection ----------------
__global__ __launch_bounds__(256) void k_final(
    const float* __restrict__ PS2, const float* __restrict__ PSUP,
    const float* __restrict__ pred, const float* __restrict__ emb,
    const float* __restrict__ Ws, const float* __restrict__ Wo,
    const float* __restrict__ b_ih, const float* __restrict__ b_hh,
    float* __restrict__ out) {
  int b = blockIdx.x, t = threadIdx.x;
  __shared__ float nh[H_], sv[EMB_];
  float gr = b_ih[t], gz = b_ih[256 + t], gn = b_ih[512 + t];
  float wc_t = 0.f;
  #pragma unroll
  for (int s = 0; s < 8; ++s) {
    const float* row = PS2 + ((size_t)(s * 64) + b) * 1024;
    gr += row[t]; gz += row[256 + t]; gn += row[512 + t];
    wc_t += row[768 + t];
  }
  float hr = b_hh[t], hz = b_hh[256 + t], hn = b_hh[512 + t];
  #pragma unroll
  for (int s = 0; s < 4; ++s) {
    const float* row = PSUP + ((size_t)(s * 64) + b) * 1792;
    hr += row[1024 + t]; hz += row[1280 + t]; hn += row[1536 + t];
  }
  float hv = pred[b * H_ + t];
  float r = sigm(gr + hr);
  float z = sigm(gz + hz);
  float n = tanhf(gn + r * hn);
  float h = (1.f - z) * n + z * hv;
  nh[t] = h;
  out[NC_ * B_ + b * H_ + t] = h;
  __syncthreads();
  {
    const float4* ws4 = (const float4*)(Ws + (size_t)t * H_);
    float s1 = 0.f;
    for (int k = 0; k < H_ / 4; ++k) {
      float4 v = ws4[k];
      s1 += nh[4*k]*v.x + nh[4*k+1]*v.y + nh[4*k+2]*v.z + nh[4*k+3]*v.w;
    }
    sv[t] = emb[b * EMB_ + t] + s1 + wc_t;
  }
  __syncthreads();
  if (t < NC_) {
    const float4* wo4 = (const float4*)(Wo + (size_t)t * EMB_);
    float s = 0.f;
    for (int k = 0; k < EMB_ / 4; ++k) {
      float4 v = wo4[k];
      s += sv[4*k]*v.x + sv[4*k+1]*v.y + sv[4*k+2]*v.z + sv[4*k+3]*v.w;
    }
    out[b * NC_ + t] = s;
  }
}

extern "C" void kernel_launch(void* const* d_in, const int* in_sizes, int n_in,
                              void* d_out, int out_size, void* d_ws, size_t ws_size,
                              hipStream_t stream) {
  (void)in_sizes; (void)n_in; (void)out_size; (void)ws_size;
  const int*   x       = (const int*)  d_in[0];
  const float* hidden  = (const float*)d_in[1];
  const float* lowres  = (const float*)d_in[2];
  const float* highres = (const float*)d_in[3];
  const float* aLow    = (const float*)d_in[4];
  const float* aHigh   = (const float*)d_in[5];
  const float* embd    = (const float*)d_in[6];
  const float* g1wih   = (const float*)d_in[7];
  const float* g1whh   = (const float*)d_in[8];
  const float* g1bih   = (const float*)d_in[9];
  const float* g1bhh   = (const float*)d_in[10];
  const float* g2wih   = (const float*)d_in[11];
  const float* g2whh   = (const float*)d_in[12];
  const float* g2bih   = (const float*)d_in[13];
  const float* g2bhh   = (const float*)d_in[14];
  const float* fwL     = (const float*)d_in[15];
  const float* fbL     = (const float*)d_in[16];
  const float* UpL     = (const float*)d_in[17];
  const float* UaL     = (const float*)d_in[18];
  const float* UfL     = (const float*)d_in[19];
  const float* nuL     = (const float*)d_in[20];
  const float* fwH     = (const float*)d_in[21];
  const float* fbH     = (const float*)d_in[22];
  const float* UpH     = (const float*)d_in[23];
  const float* UaH     = (const float*)d_in[24];
  const float* UfH     = (const float*)d_in[25];
  const float* nuH     = (const float*)d_in[26];
  const float* Wo      = (const float*)d_in[27];
  const float* Ws      = (const float*)d_in[28];
  const float* Wc      = (const float*)d_in[29];

  float* ws  = (float*)d_ws;
  float* out = (float*)d_out;
  float* w_emb  = ws + OFF_EMB;
  float* w_pred = ws + OFF_PRED;
  float* w_ps1  = ws + OFF_PS1;
  float* w_psup = ws + OFF_PSUP;
  float* w_ps2  = ws + OFF_PS2;
  float* w_ofL  = ws + OFF_OFL;
  float* w_ofH  = ws + OFF_OFH;
  float* w_ufL  = ws + OFF_UFL;
  float* w_ufH  = ws + OFF_UFH;
  float* w_eL   = ws + OFF_EL;
  float* w_eH   = ws + OFF_EH;
  float* w_ctx  = ws + OFF_CTX;
  float* w_alL  = ws + OFF_ALL;
  float* w_alH  = ws + OFF_ALH;
  bf16_t* uaLb  = (bf16_t*)(ws + OFF_UAL);
  bf16_t* uaHb  = (bf16_t*)(ws + OFF_UAH);

  k_front<<<3072, 256, 0, stream>>>(UaL, UaH, uaLb, uaHb, x, embd, w_emb,
                                    aLow, aHigh, fwL, fbL, fwH, fbH, w_ofL, w_ofH);
  k_uf<<<128, 256, 0, stream>>>(UfL, UfH, w_ofL, w_ofH, w_ufL, w_ufH);

  k_mv<<<dim3(48, 4), 256, 0, stream>>>(g1wih, g1whh, nullptr,
                                        w_emb, hidden, nullptr,
                                        768, 768, 256, 256, 4, 1536, w_ps1);
  k_act1<<<B_, 256, 0, stream>>>(w_ps1, hidden, w_pred);
  k_mv<<<dim3(56, 4), 256, 0, stream>>>(UpL, UpH, g2whh,
                                        w_pred, w_pred, w_pred,
                                        512, 512, 256, 256, 4, 1792, w_psup);

  k_ua<<<dim3(13, B_), 512, 0, stream>>>(uaLb, uaHb, lowres, highres, w_psup,
                                         w_ufL, w_ufH, nuL, nuH, w_eL, w_eH);
  k_smax<<<128, 256, 0, stream>>>(w_eL, w_eH, w_alL, w_alH);
  k_ctx<<<dim3(17, B_), 256, 0, stream>>>(w_alL, w_alH, lowres, highres, w_ctx);

  k_mv<<<dim3(32, 8), 256, 0, stream>>>(g2wih, Wc, nullptr,
                                        w_ctx, w_ctx, nullptr,
                                        768, 256, CTX_, LDC_, 8, 1024, w_ps2);
  k_final<<<B_, 256, 0, stream>>>(w_ps2, w_psup, w_pred, w_emb, Ws, Wo, g2bih, g2bhh, out);
}